// Round 5
// baseline (874.655 us; speedup 1.0000x reference)
//
#include <hip/hip_runtime.h>

typedef __attribute__((ext_vector_type(8))) short short8;
typedef __attribute__((ext_vector_type(4))) float f32x4;
typedef __attribute__((ext_vector_type(4))) unsigned short us4;

#define SCALE 0.17677669529663687f  // 1/sqrt(32)

__device__ __forceinline__ unsigned short f2bf(float f) {
    unsigned int u = __builtin_bit_cast(unsigned int, f);
    u += 0x7fffu + ((u >> 16) & 1u);           // RNE
    return (unsigned short)(u >> 16);
}

// swizzled offset into the 64x256 bf16 x/O tile (ushort units, 8-elem chunks)
__device__ __forceinline__ int xso(int row, int col) {
    return row * 256 + ((((col >> 3) ^ (row & 7)) << 3) | (col & 7));
}
// swizzled offset into the 32x256 fp32 out-staging tile (float units, 4-elem chunks)
__device__ __forceinline__ int oso(int rr, int col) {
    return rr * 256 + ((((col >> 2) ^ (((rr >> 2) & 3) << 2)) & 63) << 2) + (col & 3);
}

// ---------------- prep: tiled weights + bias gather ----------------
// weight tile layout: [colblk16][kstep8][lane64][8]  (B-fragment order, wave-contiguous)
__global__ void prep_kernel(const float* __restrict__ wq, const float* __restrict__ bq,
                            const float* __restrict__ wkv,
                            const float* __restrict__ bias_table, const int* __restrict__ rel_idx,
                            const float* __restrict__ proj_w,
                            unsigned short* __restrict__ wqT, unsigned short* __restrict__ wkT,
                            unsigned short* __restrict__ wvT, unsigned short* __restrict__ projT,
                            float* __restrict__ bias_resh, float* __restrict__ bq_s)
{
    int t = blockIdx.x * blockDim.x + threadIdx.x;   // 65536 threads
    {
        int j = t & 7, l = (t >> 3) & 63, ks = (t >> 9) & 7, nb = t >> 12;
        int k = ks * 32 + ((l >> 4) << 3) + j;
        int c = nb * 16 + (l & 15);
        wqT[t]   = f2bf(wq[k * 256 + c] * SCALE);
        wkT[t]   = f2bf(wkv[k * 512 + c]);
        wvT[t]   = f2bf(wkv[k * 512 + 256 + c]);
        projT[t] = f2bf(proj_w[k * 256 + c]);
    }
    if (t < 32768) {  // bias_resh[h][m][n][lane][r]
        int r = t & 3, l = (t >> 2) & 63, n = (t >> 8) & 3, m = (t >> 10) & 3, h = t >> 12;
        int row = m * 16 + ((l >> 4) << 2) + r;
        int col = n * 16 + (l & 15);
        bias_resh[t] = bias_table[rel_idx[row * 64 + col] * 8 + h];
    }
    if (t < 256) bq_s[t] = bq[t] * SCALE;
}

// ---------------- fused window attention ----------------
// grid 4096, 512 threads = 8 waves, wave w -> head w (one head per wave).
// LDS 72 KB -> 2 blocks/CU = 16 waves/CU = 4 waves/SIMD (50% occupancy).
// Per-wave critical path is ONE head's chain (was two).
__global__ __launch_bounds__(512, 4) void win_attn(
    const float* __restrict__ x,
    const unsigned short* __restrict__ wqT,
    const unsigned short* __restrict__ wkT,
    const unsigned short* __restrict__ wvT,
    const unsigned short* __restrict__ projT,
    const float* __restrict__ bq_s,
    const float* __restrict__ bkv,
    const float* __restrict__ bias_resh,
    const float* __restrict__ wvec,
    const float* __restrict__ proj_b,
    float* __restrict__ out)
{
    __shared__ __align__(16) unsigned short xs[64 * 256];   // x tile -> O tile -> fp32 out staging
    __shared__ __align__(16) unsigned short wbuf[8][2560];  // 5 KB per-wave scratch

    const int tid  = threadIdx.x;
    const int wave = tid >> 6;          // == head h
    const int lane = tid & 63;
    const int l16  = lane & 15;
    const int quad = lane >> 4;
    const int h    = wave;

    const float w0 = wvec[0], w1 = wvec[1];
    const float wm = fmaxf(w0, w1);
    const float e0 = __expf(w0 - wm), e1 = __expf(w1 - wm);
    const float ww0 = e0 / (e0 + e1);
    const float ww1 = e1 / (e0 + e1);

    // ---- stage x window -> LDS bf16 (swizzled) ----
    const float* xw = x + (size_t)blockIdx.x * 16384;
    #pragma unroll
    for (int i = 0; i < 8; ++i) {
        int vec = i * 512 + tid;
        int row = vec >> 6;
        int col = (vec & 63) << 2;
        f32x4 v = *(const f32x4*)(xw + row * 256 + col);
        us4 p = { f2bf(v[0]), f2bf(v[1]), f2bf(v[2]), f2bf(v[3]) };
        *(us4*)(&xs[xso(row, col)]) = p;
    }
    __syncthreads();

    unsigned short* R = wbuf[wave];
    const f32x4 fzero = {0.f, 0.f, 0.f, 0.f};

    struct Acc42 { f32x4 v[4][2]; };

    // D[64][32] = xs @ W[colblk h*2 .. h*2+1]; returns MFMA C-layout
    auto gemm_qkv = [&](const unsigned short* __restrict__ Wt) -> Acc42 {
        Acc42 A;
        #pragma unroll
        for (int m = 0; m < 4; ++m)
            #pragma unroll
            for (int n = 0; n < 2; ++n) A.v[m][n] = fzero;
        const unsigned short* Wb = Wt + h * 2 * 4096;
        #pragma unroll
        for (int k = 0; k < 8; ++k) {
            short8 a[4], b[2];
            #pragma unroll
            for (int m = 0; m < 4; ++m)
                a[m] = *(const short8*)(&xs[xso(m * 16 + l16, k * 32 + quad * 8)]);
            #pragma unroll
            for (int n = 0; n < 2; ++n)
                b[n] = *(const short8*)(Wb + (n * 8 + k) * 512 + lane * 8);
            #pragma unroll
            for (int m = 0; m < 4; ++m)
                #pragma unroll
                for (int n = 0; n < 2; ++n)
                    A.v[m][n] = __builtin_amdgcn_mfma_f32_16x16x32_bf16(a[m], b[n], A.v[m][n], 0, 0, 0);
        }
        return A;
    };

    // ---- Q -> R (qs[64][40]) -> aq frags ----
    {
        Acc42 A = gemm_qkv(wqT);
        #pragma unroll
        for (int n = 0; n < 2; ++n) {
            float bv = bq_s[h * 32 + n * 16 + l16];
            #pragma unroll
            for (int m = 0; m < 4; ++m)
                #pragma unroll
                for (int r = 0; r < 4; ++r)
                    R[(m * 16 + quad * 4 + r) * 40 + n * 16 + l16] = f2bf(A.v[m][n][r] + bv);
        }
    }
    short8 aq[4];
    #pragma unroll
    for (int m = 0; m < 4; ++m)
        aq[m] = *(const short8*)(&R[(m * 16 + l16) * 40 + quad * 8]);

    // ---- K -> R (reuse) -> bk frags ----
    {
        Acc42 A = gemm_qkv(wkT);
        #pragma unroll
        for (int n = 0; n < 2; ++n) {
            float bv = bkv[h * 32 + n * 16 + l16];
            #pragma unroll
            for (int m = 0; m < 4; ++m)
                #pragma unroll
                for (int r = 0; r < 4; ++r)
                    R[(m * 16 + quad * 4 + r) * 40 + n * 16 + l16] = f2bf(A.v[m][n][r] + bv);
        }
    }
    short8 bk[4];
    #pragma unroll
    for (int n = 0; n < 4; ++n)
        bk[n] = *(const short8*)(&R[(n * 16 + l16) * 40 + quad * 8]);

    // ---- V -> R as vt[32 dims][72] (transposed) -> vb frags ----
    {
        Acc42 A = gemm_qkv(wvT);
        #pragma unroll
        for (int n = 0; n < 2; ++n) {
            float bv = bkv[256 + h * 32 + n * 16 + l16];
            #pragma unroll
            for (int m = 0; m < 4; ++m)
                #pragma unroll
                for (int r = 0; r < 4; ++r)
                    R[(n * 16 + l16) * 72 + m * 16 + quad * 4 + r] = f2bf(A.v[m][n][r] + bv);
        }
    }
    short8 vb[2][2];
    #pragma unroll
    for (int half = 0; half < 2; ++half)
        #pragma unroll
        for (int n = 0; n < 2; ++n)
            vb[half][n] = *(const short8*)(&R[(n * 16 + l16) * 72 + half * 32 + quad * 8]);

    // ---- per-row-block fused S = QK^T + bias -> dual-path softmax -> packed bf16 P ----
    unsigned int pk[4][2][4];   // [m][half][r] : packed bf16 pair (n2=0 | n2=1<<16)
    #pragma unroll
    for (int m = 0; m < 4; ++m) {
        f32x4 sm[4];
        #pragma unroll
        for (int n = 0; n < 4; ++n)
            sm[n] = __builtin_amdgcn_mfma_f32_16x16x32_bf16(aq[m], bk[n], fzero, 0, 0, 0);
        #pragma unroll
        for (int n = 0; n < 4; ++n) {
            f32x4 bb = *(const f32x4*)(bias_resh + h * 4096 + (m * 4 + n) * 256 + lane * 4);
            sm[n] += bb;
        }
        #pragma unroll
        for (int r = 0; r < 4; ++r) {
            float s0 = sm[0][r], s1 = sm[1][r], s2 = sm[2][r], s3 = sm[3][r];
            float mx = fmaxf(fmaxf(s0, s1), fmaxf(s2, s3));
            mx = fmaxf(mx, __shfl_xor(mx, 1));
            mx = fmaxf(mx, __shfl_xor(mx, 2));
            mx = fmaxf(mx, __shfl_xor(mx, 4));
            mx = fmaxf(mx, __shfl_xor(mx, 8));
            float ee0 = __expf(s0 - mx), ee1 = __expf(s1 - mx);
            float ee2 = __expf(s2 - mx), ee3 = __expf(s3 - mx);
            float smm = ee0 + ee1 + ee2 + ee3;
            smm += __shfl_xor(smm, 1);
            smm += __shfl_xor(smm, 2);
            smm += __shfl_xor(smm, 4);
            smm += __shfl_xor(smm, 8);
            float rf = ww0 / smm;
            float r0 = fmaxf(s0, 0.f), r1 = fmaxf(s1, 0.f);
            float r2 = fmaxf(s2, 0.f), r3 = fmaxf(s3, 0.f);
            float p0 = rf * ee0 + ww1 * r0 * r0;
            float p1 = rf * ee1 + ww1 * r1 * r1;
            float p2 = rf * ee2 + ww1 * r2 * r2;
            float p3 = rf * ee3 + ww1 * r3 * r3;
            pk[m][0][r] = (unsigned int)f2bf(p0) | ((unsigned int)f2bf(p1) << 16);
            pk[m][1][r] = (unsigned int)f2bf(p2) | ((unsigned int)f2bf(p3) << 16);
        }
    }

    // ---- PV in two 32-token halves through R ----
    f32x4 oa[4][2];
    #pragma unroll
    for (int m = 0; m < 4; ++m)
        #pragma unroll
        for (int n = 0; n < 2; ++n) oa[m][n] = fzero;
    #pragma unroll
    for (int half = 0; half < 2; ++half) {
        #pragma unroll
        for (int m = 0; m < 4; ++m)
            #pragma unroll
            for (int n2 = 0; n2 < 2; ++n2)
                #pragma unroll
                for (int r = 0; r < 4; ++r)
                    R[(m * 16 + quad * 4 + r) * 40 + n2 * 16 + l16] =
                        (unsigned short)(pk[m][half][r] >> (n2 * 16));
        short8 ap[4];
        #pragma unroll
        for (int m = 0; m < 4; ++m)
            ap[m] = *(const short8*)(&R[(m * 16 + l16) * 40 + quad * 8]);
        #pragma unroll
        for (int m = 0; m < 4; ++m)
            #pragma unroll
            for (int n = 0; n < 2; ++n)
                oa[m][n] = __builtin_amdgcn_mfma_f32_16x16x32_bf16(ap[m], vb[half][n], oa[m][n], 0, 0, 0);
    }

    // ---- O -> xs (bf16, swizzled); head h owns cols [32h, 32h+32) ----
    __syncthreads();
    #pragma unroll
    for (int m = 0; m < 4; ++m)
        #pragma unroll
        for (int n = 0; n < 2; ++n)
            #pragma unroll
            for (int r = 0; r < 4; ++r)
                xs[xso(m * 16 + quad * 4 + r, h * 32 + n * 16 + l16)] = f2bf(oa[m][n][r]);
    __syncthreads();

    // ---- proj GEMM: wave w -> cols [32w, 32w+32) ----
    f32x4 pacc[4][2];
    #pragma unroll
    for (int m = 0; m < 4; ++m)
        #pragma unroll
        for (int n = 0; n < 2; ++n) pacc[m][n] = fzero;
    #pragma unroll
    for (int k = 0; k < 8; ++k) {
        short8 a[4], b[2];
        #pragma unroll
        for (int m = 0; m < 4; ++m)
            a[m] = *(const short8*)(&xs[xso(m * 16 + l16, k * 32 + quad * 8)]);
        #pragma unroll
        for (int n = 0; n < 2; ++n)
            b[n] = *(const short8*)(projT + ((wave * 2 + n) * 8 + k) * 512 + lane * 8);
        #pragma unroll
        for (int m = 0; m < 4; ++m)
            #pragma unroll
            for (int n = 0; n < 2; ++n)
                pacc[m][n] = __builtin_amdgcn_mfma_f32_16x16x32_bf16(a[m], b[n], pacc[m][n], 0, 0, 0);
    }

    // ---- epilogue: stage fp32 rows through xs, fully coalesced float4 stores ----
    float* os = (float*)xs;
    float* ow = out + (size_t)blockIdx.x * 16384;
    float pb[2];
    #pragma unroll
    for (int n = 0; n < 2; ++n) pb[n] = proj_b[wave * 32 + n * 16 + l16];

    #pragma unroll
    for (int half = 0; half < 2; ++half) {
        __syncthreads();   // previous readers of xs/os done
        #pragma unroll
        for (int mh = 0; mh < 2; ++mh) {
            int m = half * 2 + mh;
            #pragma unroll
            for (int n = 0; n < 2; ++n)
                #pragma unroll
                for (int r = 0; r < 4; ++r)
                    os[oso(mh * 16 + quad * 4 + r, wave * 32 + n * 16 + l16)] =
                        pacc[m][n][r] + pb[n];
        }
        __syncthreads();
        #pragma unroll
        for (int i = 0; i < 4; ++i) {
            int idx = i * 512 + tid;               // 2048 float4 over 32x256
            int rr = idx >> 6;
            int c4 = idx & 63;
            f32x4 v = *(const f32x4*)(&os[rr * 256 + ((c4 ^ (((rr >> 2) & 3) << 2)) << 2)]);
            *(f32x4*)(&ow[(half * 32 + rr) * 256 + c4 * 4]) = v;
        }
    }
}

extern "C" void kernel_launch(void* const* d_in, const int* in_sizes, int n_in,
                              void* d_out, int out_size, void* d_ws, size_t ws_size,
                              hipStream_t stream)
{
    const float* x          = (const float*)d_in[0];
    const float* wq         = (const float*)d_in[1];
    const float* bq         = (const float*)d_in[2];
    const float* wkv        = (const float*)d_in[3];
    const float* bkv        = (const float*)d_in[4];
    const float* bias_table = (const float*)d_in[5];
    const float* wv         = (const float*)d_in[6];
    const float* proj_w     = (const float*)d_in[7];
    const float* proj_b     = (const float*)d_in[8];
    const int*   rel_idx    = (const int*)d_in[9];

    char* ws = (char*)d_ws;
    unsigned short* wqT   = (unsigned short*)(ws);
    unsigned short* wkT   = (unsigned short*)(ws + 131072);
    unsigned short* wvT   = (unsigned short*)(ws + 262144);
    unsigned short* projT = (unsigned short*)(ws + 393216);
    float* bias_resh      = (float*)(ws + 524288);
    float* bq_s           = (float*)(ws + 655360);

    prep_kernel<<<256, 256, 0, stream>>>(wq, bq, wkv, bias_table, rel_idx, proj_w,
                                         wqT, wkT, wvT, projT, bias_resh, bq_s);
    win_attn<<<4096, 512, 0, stream>>>(x, wqT, wkT, wvT, projT, bq_s, bkv,
                                       bias_resh, wv, proj_b, (float*)d_out);
}

// Round 6
// 732.825 us; speedup vs baseline: 1.1935x; 1.1935x over previous
//
#include <hip/hip_runtime.h>

typedef __attribute__((ext_vector_type(8))) short short8;
typedef __attribute__((ext_vector_type(4))) float f32x4;
typedef __attribute__((ext_vector_type(4))) unsigned short us4;

#define SCALE 0.17677669529663687f  // 1/sqrt(32)

__device__ __forceinline__ unsigned short f2bf(float f) {
    unsigned int u = __builtin_bit_cast(unsigned int, f);
    u += 0x7fffu + ((u >> 16) & 1u);           // RNE
    return (unsigned short)(u >> 16);
}

// swizzled offset into the 64x256 bf16 x/O tile (ushort units, 8-elem chunks)
__device__ __forceinline__ int xso(int row, int col) {
    return row * 256 + ((((col >> 3) ^ (row & 7)) << 3) | (col & 7));
}
// swizzled offset into the 32x256 fp32 out-staging tile (float units, 4-elem chunks)
__device__ __forceinline__ int oso(int rr, int col) {
    return rr * 256 + ((((col >> 2) ^ (((rr >> 2) & 3) << 2)) & 63) << 2) + (col & 3);
}

// ---------------- prep: tiled weights + bias gather ----------------
// weight tile layout: [colblk16][kstep8][lane64][8]  (B-fragment order, wave-contiguous)
__global__ void prep_kernel(const float* __restrict__ wq, const float* __restrict__ bq,
                            const float* __restrict__ wkv,
                            const float* __restrict__ bias_table, const int* __restrict__ rel_idx,
                            const float* __restrict__ proj_w,
                            unsigned short* __restrict__ wqT, unsigned short* __restrict__ wkT,
                            unsigned short* __restrict__ wvT, unsigned short* __restrict__ projT,
                            float* __restrict__ bias_resh, float* __restrict__ bq_s)
{
    int t = blockIdx.x * blockDim.x + threadIdx.x;   // 65536 threads
    {
        int j = t & 7, l = (t >> 3) & 63, ks = (t >> 9) & 7, nb = t >> 12;
        int k = ks * 32 + ((l >> 4) << 3) + j;
        int c = nb * 16 + (l & 15);
        wqT[t]   = f2bf(wq[k * 256 + c] * SCALE);
        wkT[t]   = f2bf(wkv[k * 512 + c]);
        wvT[t]   = f2bf(wkv[k * 512 + 256 + c]);
        projT[t] = f2bf(proj_w[k * 256 + c]);
    }
    if (t < 32768) {  // bias_resh[h][m][n][lane][r]
        int r = t & 3, l = (t >> 2) & 63, n = (t >> 8) & 3, m = (t >> 10) & 3, h = t >> 12;
        int row = m * 16 + ((l >> 4) << 2) + r;
        int col = n * 16 + (l & 15);
        bias_resh[t] = bias_table[rel_idx[row * 64 + col] * 8 + h];
    }
    if (t < 256) bq_s[t] = bq[t] * SCALE;
}

// ---------------- fused window attention ----------------
// grid 4096, 512 threads = 8 waves, wave w -> head w.  LDS 72 KB -> 2 blocks/CU,
// 16 waves/CU = 4/SIMD.  Budget 128 regs; phase order Q->K->S->V->PV keeps every
// phase's liveness under ~110 regs (V transient never overlaps aq/bk/bb).
__global__ __launch_bounds__(512, 4) void win_attn(
    const float* __restrict__ x,
    const unsigned short* __restrict__ wqT,
    const unsigned short* __restrict__ wkT,
    const unsigned short* __restrict__ wvT,
    const unsigned short* __restrict__ projT,
    const float* __restrict__ bq_s,
    const float* __restrict__ bkv,
    const float* __restrict__ bias_resh,
    const float* __restrict__ wvec,
    const float* __restrict__ proj_b,
    float* __restrict__ out)
{
    __shared__ __align__(16) unsigned short xs[64 * 256];   // x tile -> O tile -> fp32 out staging
    __shared__ __align__(16) unsigned short wbuf[8][2560];  // 5 KB per-wave scratch

    const int tid  = threadIdx.x;
    const int wave = tid >> 6;          // == head h
    const int lane = tid & 63;
    const int l16  = lane & 15;
    const int quad = lane >> 4;
    const int h    = wave;

    const float w0 = wvec[0], w1 = wvec[1];
    const float wm = fmaxf(w0, w1);
    const float e0 = __expf(w0 - wm), e1 = __expf(w1 - wm);
    const float ww0 = e0 / (e0 + e1);
    const float ww1 = e1 / (e0 + e1);

    // ---- stage x window -> LDS bf16 (swizzled) ----
    const float* xw = x + (size_t)blockIdx.x * 16384;
    #pragma unroll
    for (int i = 0; i < 8; ++i) {
        int vec = i * 512 + tid;
        int row = vec >> 6;
        int col = (vec & 63) << 2;
        f32x4 v = *(const f32x4*)(xw + row * 256 + col);
        us4 p = { f2bf(v[0]), f2bf(v[1]), f2bf(v[2]), f2bf(v[3]) };
        *(us4*)(&xs[xso(row, col)]) = p;
    }
    __syncthreads();

    unsigned short* R = wbuf[wave];
    const f32x4 fzero = {0.f, 0.f, 0.f, 0.f};

    struct Acc42 { f32x4 v[4][2]; };

    // D[64][32] = xs @ W[colblk h*2 .. h*2+1]; returns MFMA C-layout
    auto gemm_qkv = [&](const unsigned short* __restrict__ Wt) -> Acc42 {
        Acc42 A;
        #pragma unroll
        for (int m = 0; m < 4; ++m)
            #pragma unroll
            for (int n = 0; n < 2; ++n) A.v[m][n] = fzero;
        const unsigned short* Wb = Wt + h * 2 * 4096;
        #pragma unroll
        for (int k = 0; k < 8; ++k) {
            short8 a[4], b[2];
            #pragma unroll
            for (int m = 0; m < 4; ++m)
                a[m] = *(const short8*)(&xs[xso(m * 16 + l16, k * 32 + quad * 8)]);
            #pragma unroll
            for (int n = 0; n < 2; ++n)
                b[n] = *(const short8*)(Wb + (n * 8 + k) * 512 + lane * 8);
            #pragma unroll
            for (int m = 0; m < 4; ++m)
                #pragma unroll
                for (int n = 0; n < 2; ++n)
                    A.v[m][n] = __builtin_amdgcn_mfma_f32_16x16x32_bf16(a[m], b[n], A.v[m][n], 0, 0, 0);
        }
        return A;
    };

    // ---- Q -> R (qs[64][40]) -> aq frags ----
    {
        Acc42 A = gemm_qkv(wqT);
        #pragma unroll
        for (int n = 0; n < 2; ++n) {
            float bv = bq_s[h * 32 + n * 16 + l16];
            #pragma unroll
            for (int m = 0; m < 4; ++m)
                #pragma unroll
                for (int r = 0; r < 4; ++r)
                    R[(m * 16 + quad * 4 + r) * 40 + n * 16 + l16] = f2bf(A.v[m][n][r] + bv);
        }
    }
    short8 aq[4];
    #pragma unroll
    for (int m = 0; m < 4; ++m)
        aq[m] = *(const short8*)(&R[(m * 16 + l16) * 40 + quad * 8]);
    __builtin_amdgcn_sched_barrier(0);

    // ---- K -> R (reuse) -> bk frags ----
    {
        Acc42 A = gemm_qkv(wkT);
        #pragma unroll
        for (int n = 0; n < 2; ++n) {
            float bv = bkv[h * 32 + n * 16 + l16];
            #pragma unroll
            for (int m = 0; m < 4; ++m)
                #pragma unroll
                for (int r = 0; r < 4; ++r)
                    R[(m * 16 + quad * 4 + r) * 40 + n * 16 + l16] = f2bf(A.v[m][n][r] + bv);
        }
    }
    short8 bk[4];
    #pragma unroll
    for (int n = 0; n < 4; ++n)
        bk[n] = *(const short8*)(&R[(n * 16 + l16) * 40 + quad * 8]);
    __builtin_amdgcn_sched_barrier(0);

    // ---- per-row-block fused S = QK^T + bias (as MFMA C-seed) -> dual-path softmax
    //      -> packed bf16 P.  Only sm[4]+bb (32 regs) transient per m. ----
    unsigned int pk[4][2][4];   // [m][half][r] : packed bf16 pair (n2=0 | n2=1<<16)
    #pragma unroll
    for (int m = 0; m < 4; ++m) {
        f32x4 sm[4];
        #pragma unroll
        for (int n = 0; n < 4; ++n) {
            f32x4 bb = *(const f32x4*)(bias_resh + h * 4096 + (m * 4 + n) * 256 + lane * 4);
            sm[n] = __builtin_amdgcn_mfma_f32_16x16x32_bf16(aq[m], bk[n], bb, 0, 0, 0);
        }
        #pragma unroll
        for (int r = 0; r < 4; ++r) {
            float s0 = sm[0][r], s1 = sm[1][r], s2 = sm[2][r], s3 = sm[3][r];
            float mx = fmaxf(fmaxf(s0, s1), fmaxf(s2, s3));
            mx = fmaxf(mx, __shfl_xor(mx, 1));
            mx = fmaxf(mx, __shfl_xor(mx, 2));
            mx = fmaxf(mx, __shfl_xor(mx, 4));
            mx = fmaxf(mx, __shfl_xor(mx, 8));
            float ee0 = __expf(s0 - mx), ee1 = __expf(s1 - mx);
            float ee2 = __expf(s2 - mx), ee3 = __expf(s3 - mx);
            float smm = ee0 + ee1 + ee2 + ee3;
            smm += __shfl_xor(smm, 1);
            smm += __shfl_xor(smm, 2);
            smm += __shfl_xor(smm, 4);
            smm += __shfl_xor(smm, 8);
            float rf = ww0 / smm;
            float r0 = fmaxf(s0, 0.f), r1 = fmaxf(s1, 0.f);
            float r2 = fmaxf(s2, 0.f), r3 = fmaxf(s3, 0.f);
            float p0 = rf * ee0 + ww1 * r0 * r0;
            float p1 = rf * ee1 + ww1 * r1 * r1;
            float p2 = rf * ee2 + ww1 * r2 * r2;
            float p3 = rf * ee3 + ww1 * r3 * r3;
            pk[m][0][r] = (unsigned int)f2bf(p0) | ((unsigned int)f2bf(p1) << 16);
            pk[m][1][r] = (unsigned int)f2bf(p2) | ((unsigned int)f2bf(p3) << 16);
        }
        __builtin_amdgcn_sched_barrier(0);
    }

    // ---- V -> R as vt[32 dims][72] (transposed) -> vb frags.  Runs AFTER softmax:
    //      its 56-reg transient overlaps only pk(32), never aq/bk/bb. ----
    {
        Acc42 A = gemm_qkv(wvT);
        #pragma unroll
        for (int n = 0; n < 2; ++n) {
            float bv = bkv[256 + h * 32 + n * 16 + l16];
            #pragma unroll
            for (int m = 0; m < 4; ++m)
                #pragma unroll
                for (int r = 0; r < 4; ++r)
                    R[(n * 16 + l16) * 72 + m * 16 + quad * 4 + r] = f2bf(A.v[m][n][r] + bv);
        }
    }
    short8 vb[2][2];
    #pragma unroll
    for (int half = 0; half < 2; ++half)
        #pragma unroll
        for (int n = 0; n < 2; ++n)
            vb[half][n] = *(const short8*)(&R[(n * 16 + l16) * 72 + half * 32 + quad * 8]);
    __builtin_amdgcn_sched_barrier(0);

    // ---- PV in two 32-token halves through R ----
    f32x4 oa[4][2];
    #pragma unroll
    for (int m = 0; m < 4; ++m)
        #pragma unroll
        for (int n = 0; n < 2; ++n) oa[m][n] = fzero;
    #pragma unroll
    for (int half = 0; half < 2; ++half) {
        #pragma unroll
        for (int m = 0; m < 4; ++m)
            #pragma unroll
            for (int n2 = 0; n2 < 2; ++n2)
                #pragma unroll
                for (int r = 0; r < 4; ++r)
                    R[(m * 16 + quad * 4 + r) * 40 + n2 * 16 + l16] =
                        (unsigned short)(pk[m][half][r] >> (n2 * 16));
        short8 ap[4];
        #pragma unroll
        for (int m = 0; m < 4; ++m)
            ap[m] = *(const short8*)(&R[(m * 16 + l16) * 40 + quad * 8]);
        #pragma unroll
        for (int m = 0; m < 4; ++m)
            #pragma unroll
            for (int n = 0; n < 2; ++n)
                oa[m][n] = __builtin_amdgcn_mfma_f32_16x16x32_bf16(ap[m], vb[half][n], oa[m][n], 0, 0, 0);
    }

    // ---- O -> xs (bf16, swizzled); head h owns cols [32h, 32h+32) ----
    __syncthreads();
    #pragma unroll
    for (int m = 0; m < 4; ++m)
        #pragma unroll
        for (int n = 0; n < 2; ++n)
            #pragma unroll
            for (int r = 0; r < 4; ++r)
                xs[xso(m * 16 + quad * 4 + r, h * 32 + n * 16 + l16)] = f2bf(oa[m][n][r]);
    __syncthreads();

    // ---- proj GEMM: wave w -> cols [32w, 32w+32) ----
    f32x4 pacc[4][2];
    #pragma unroll
    for (int m = 0; m < 4; ++m)
        #pragma unroll
        for (int n = 0; n < 2; ++n) pacc[m][n] = fzero;
    #pragma unroll
    for (int k = 0; k < 8; ++k) {
        short8 a[4], b[2];
        #pragma unroll
        for (int m = 0; m < 4; ++m)
            a[m] = *(const short8*)(&xs[xso(m * 16 + l16, k * 32 + quad * 8)]);
        #pragma unroll
        for (int n = 0; n < 2; ++n)
            b[n] = *(const short8*)(projT + ((wave * 2 + n) * 8 + k) * 512 + lane * 8);
        #pragma unroll
        for (int m = 0; m < 4; ++m)
            #pragma unroll
            for (int n = 0; n < 2; ++n)
                pacc[m][n] = __builtin_amdgcn_mfma_f32_16x16x32_bf16(a[m], b[n], pacc[m][n], 0, 0, 0);
    }

    // ---- epilogue: stage fp32 rows through xs, fully coalesced float4 stores ----
    float* os = (float*)xs;
    float* ow = out + (size_t)blockIdx.x * 16384;
    float pb[2];
    #pragma unroll
    for (int n = 0; n < 2; ++n) pb[n] = proj_b[wave * 32 + n * 16 + l16];

    #pragma unroll
    for (int half = 0; half < 2; ++half) {
        __syncthreads();   // previous readers of xs/os done
        #pragma unroll
        for (int mh = 0; mh < 2; ++mh) {
            int m = half * 2 + mh;
            #pragma unroll
            for (int n = 0; n < 2; ++n)
                #pragma unroll
                for (int r = 0; r < 4; ++r)
                    os[oso(mh * 16 + quad * 4 + r, wave * 32 + n * 16 + l16)] =
                        pacc[m][n][r] + pb[n];
        }
        __syncthreads();
        #pragma unroll
        for (int i = 0; i < 4; ++i) {
            int idx = i * 512 + tid;               // 2048 float4 over 32x256
            int rr = idx >> 6;
            int c4 = idx & 63;
            f32x4 v = *(const f32x4*)(&os[rr * 256 + ((c4 ^ (((rr >> 2) & 3) << 2)) << 2)]);
            *(f32x4*)(&ow[(half * 32 + rr) * 256 + c4 * 4]) = v;
        }
    }
}

extern "C" void kernel_launch(void* const* d_in, const int* in_sizes, int n_in,
                              void* d_out, int out_size, void* d_ws, size_t ws_size,
                              hipStream_t stream)
{
    const float* x          = (const float*)d_in[0];
    const float* wq         = (const float*)d_in[1];
    const float* bq         = (const float*)d_in[2];
    const float* wkv        = (const float*)d_in[3];
    const float* bkv        = (const float*)d_in[4];
    const float* bias_table = (const float*)d_in[5];
    const float* wv         = (const float*)d_in[6];
    const float* proj_w     = (const float*)d_in[7];
    const float* proj_b     = (const float*)d_in[8];
    const int*   rel_idx    = (const int*)d_in[9];

    char* ws = (char*)d_ws;
    unsigned short* wqT   = (unsigned short*)(ws);
    unsigned short* wkT   = (unsigned short*)(ws + 131072);
    unsigned short* wvT   = (unsigned short*)(ws + 262144);
    unsigned short* projT = (unsigned short*)(ws + 393216);
    float* bias_resh      = (float*)(ws + 524288);
    float* bq_s           = (float*)(ws + 655360);

    prep_kernel<<<256, 256, 0, stream>>>(wq, bq, wkv, bias_table, rel_idx, proj_w,
                                         wqT, wkT, wvT, projT, bias_resh, bq_s);
    win_attn<<<4096, 512, 0, stream>>>(x, wqT, wkT, wvT, projT, bq_s, bkv,
                                       bias_resh, wv, proj_b, (float*)d_out);
}